// Round 5
// baseline (210.112 us; speedup 1.0000x reference)
//
#include <hip/hip_runtime.h>

// YOLO loss: pred/target (4096, 30, 14, 14) f32 -> scalar. Memory-bound.
// R5: persistent streaming. R1-R4 all plateaued at 2.5-2.8 TB/s total-read
// regardless of occupancy/VGPR/load-type -> not latency-bound. Suspect convoy
// effect: "burst once, wait, die" blocks leave the memory system idle during
// compute/retire/relaunch phases. Fix: 512 persistent blocks x 8 images each,
// distance-1 software pipeline: box planes of image i+1 DMA'd to the other LDS
// buffer and class planes of i+1 loaded to registers while computing image i.
// Top-of-iteration barrier drains loads that had a full compute phase to fly.

#define S_GRID 14
#define SS 196            // S*S
#define N_BATCH 4096
#define IMGS_PER_BLK 8
#define NBLK (N_BATCH / IMGS_PER_BLK)   // 512
#define LAMBDA_COORD 5.0f
#define LAMBDA_NOOBJ 0.5f
// per image: 1470 quads (30 planes x 49). box = quads 0..489 (staged, padded
// to 512); class = quads 490..1469 (980, register-streamed).

#define GLOAD_LDS16(g, l)                                              \
    __builtin_amdgcn_global_load_lds(                                  \
        (const __attribute__((address_space(1))) void*)(g),            \
        (__attribute__((address_space(3))) void*)(l), 16, 0, 0)

__global__ __launch_bounds__(256) void yolo_loss_kernel(
    const float* __restrict__ pred,
    const float* __restrict__ tgt,
    float* __restrict__ part)
{
    const int tid = threadIdx.x;
    const int img0 = blockIdx.x * IMGS_PER_BLK;

    // double-buffered box staging: [buf][tensor(pred=0,tgt=1)][2048 floats]
    __shared__ __align__(16) float sb[2][2][2048];
    __shared__ float wsum[4];

    // invariant per-thread constants
    int c4k[4];   // cell-quad (i%49) for class quad indices tid+256k
#pragma unroll
    for (int k = 0; k < 4; ++k) c4k[k] = (tid + k * 256) % 49;

    const float4* pb = (const float4*)pred;
    const float4* tb = (const float4*)tgt;

    // ---- prologue: stage image img0 (buf 0) + class regs for img0 ----
    {
        const float4* p4 = pb + (size_t)img0 * 1470;
        const float4* t4 = tb + (size_t)img0 * 1470;
#pragma unroll
        for (int k = 0; k < 2; ++k) {
            const int i = tid + k * 256;
            GLOAD_LDS16(p4 + i, &sb[0][0][4 * i]);
            GLOAD_LDS16(t4 + i, &sb[0][1][4 * i]);
        }
    }
    float4 cp[2][4], ct[2][4];
#pragma unroll
    for (int k = 0; k < 4; ++k) {
        const int i = tid + k * 256;
        if (i < 980) {
            cp[0][k] = pb[(size_t)img0 * 1470 + 490 + i];
            ct[0][k] = tb[(size_t)img0 * 1470 + 490 + i];
        }
    }

    float total = 0.f;

#pragma unroll
    for (int it = 0; it < IMGS_PER_BLK; ++it) {
        const int cur = it & 1;
        const int nxt = cur ^ 1;

        __syncthreads();   // drains vmcnt: buf[cur] + class regs [cur] valid

        // ---- issue image it+1 (flies during compute of image it) ----
        if (it + 1 < IMGS_PER_BLK) {
            const size_t nb = (size_t)(img0 + it + 1) * 1470;
            const float4* p4 = pb + nb;
            const float4* t4 = tb + nb;
#pragma unroll
            for (int k = 0; k < 2; ++k) {
                const int i = tid + k * 256;
                GLOAD_LDS16(p4 + i, &sb[nxt][0][4 * i]);
                GLOAD_LDS16(t4 + i, &sb[nxt][1][4 * i]);
            }
#pragma unroll
            for (int k = 0; k < 4; ++k) {
                const int i = tid + k * 256;
                if (i < 980) {
                    cp[nxt][k] = pb[nb + 490 + i];
                    ct[nxt][k] = tb[nb + 490 + i];
                }
            }
        }

        // ---- class term: obj[cell] * (p-t)^2 (obj from staged tgt conf) ----
        const float* sbp = sb[cur][0];
        const float* sbt = sb[cur][1];
#pragma unroll
        for (int k = 0; k < 4; ++k) {
            const int i = tid + k * 256;
            if (i < 980) {
                const float* objp = &sbt[4 * SS + 4 * c4k[k]];
                const float4 p = cp[cur][k], t = ct[cur][k];
                const float d0 = p.x - t.x, d1 = p.y - t.y;
                const float d2 = p.z - t.z, d3 = p.w - t.w;
                const float a0 = (objp[0] > 0.f) ? d0 * d0 : 0.f;
                const float a1 = (objp[1] > 0.f) ? d1 * d1 : 0.f;
                const float a2 = (objp[2] > 0.f) ? d2 * d2 : 0.f;
                const float a3 = (objp[3] > 0.f) ? d3 * d3 : 0.f;
                total += (a0 + a1) + (a2 + a3);
            }
        }

        // ---- box/conf terms: one cell per thread (tid < 196) ----
        if (tid < SS) {
            const int c = tid;
            float P[10], T[10];
#pragma unroll
            for (int d = 0; d < 10; ++d) {
                P[d] = sbp[d * SS + c];
                T[d] = sbt[d * SS + c];
            }

            const float tconf = T[4];
            const float obj   = (tconf > 0.f)  ? 1.f : 0.f;
            const float noobj = (tconf == 0.f) ? 1.f : 0.f;

            const float dc0 = P[4] - T[4];
            const float dc1 = P[9] - T[9];
            const float noobj_term = noobj * (dc0 * dc0 + dc1 * dc1);

            const float tcx = T[0] * (1.f / S_GRID);
            const float tcy = T[1] * (1.f / S_GRID);
            const float tltx = tcx - 0.5f * T[2], trbx = tcx + 0.5f * T[2];
            const float tlty = tcy - 0.5f * T[3], trby = tcy + 0.5f * T[3];
            const float tarea = (trbx - tltx) * (trby - tlty);

            float iou0 = 0.f, iou1 = 0.f;
#pragma unroll
            for (int b = 0; b < 2; ++b) {
                const int o = 5 * b;
                const float pcx = P[o + 0] * (1.f / S_GRID);
                const float pcy = P[o + 1] * (1.f / S_GRID);
                const float pltx = pcx - 0.5f * P[o + 2], prbx = pcx + 0.5f * P[o + 2];
                const float plty = pcy - 0.5f * P[o + 3], prby = pcy + 0.5f * P[o + 3];
                const float ltx = fmaxf(tltx, pltx), rbx = fminf(trbx, prbx);
                const float lty = fmaxf(tlty, plty), rby = fminf(trby, prby);
                const float w = fmaxf(rbx - ltx, 0.f), h = fmaxf(rby - lty, 0.f);
                const float inter = w * h;
                const float parea = (prbx - pltx) * (prby - plty);
                const float uni = tarea + parea - inter;
                const float iou = inter / ((uni == 0.f) ? 1.f : uni);
                if (b == 0) iou0 = iou; else iou1 = iou;
            }

            const bool r = (iou1 > iou0);         // jnp.argmax: first max on tie
            const float miou = fmaxf(iou0, iou1);

            const float bpr0 = r ? P[5] : P[0];
            const float bpr1 = r ? P[6] : P[1];
            const float bpr2 = r ? P[7] : P[2];
            const float bpr3 = r ? P[8] : P[3];
            const float bpr4 = r ? P[9] : P[4];
            const float btr0 = r ? T[5] : T[0];
            const float btr1 = r ? T[6] : T[1];
            const float btr2 = r ? T[7] : T[2];
            const float btr3 = r ? T[8] : T[3];

            const float dx = bpr0 - btr0, dy = bpr1 - btr1;
            const float dw = bpr2 - btr2, dh = bpr3 - btr3;
            const float dxy = dx * dx + dy * dy;
            const float dwh = dw * dw + dh * dh;
            const float dconf = bpr4 - miou;

            total += obj * (LAMBDA_COORD * (dxy + dwh) + dconf * dconf)
                   + LAMBDA_NOOBJ * noobj_term;
        }
    }

    // ---- reduce: wave(64) shuffle -> LDS -> one plain store per block ----
#pragma unroll
    for (int off = 32; off > 0; off >>= 1)
        total += __shfl_down(total, off);

    const int wid  = tid >> 6;
    const int lane = tid & 63;
    if (lane == 0) wsum[wid] = total;
    __syncthreads();
    if (tid == 0)
        part[blockIdx.x] = (wsum[0] + wsum[1]) + (wsum[2] + wsum[3]);
}

__global__ __launch_bounds__(256) void reduce_kernel(
    const float* __restrict__ part, float* __restrict__ out)
{
    const int tid = threadIdx.x;
    float s = part[tid] + part[tid + 256];     // NBLK = 512 partials
#pragma unroll
    for (int off = 32; off > 0; off >>= 1)
        s += __shfl_down(s, off);
    __shared__ float w[4];
    if ((tid & 63) == 0) w[tid >> 6] = s;
    __syncthreads();
    if (tid == 0)
        out[0] = ((w[0] + w[1]) + (w[2] + w[3])) * (1.0f / N_BATCH);
}

extern "C" void kernel_launch(void* const* d_in, const int* in_sizes, int n_in,
                              void* d_out, int out_size, void* d_ws, size_t ws_size,
                              hipStream_t stream) {
    const float* pred = (const float*)d_in[0];
    const float* tgt  = (const float*)d_in[1];
    float* out  = (float*)d_out;
    float* part = (float*)d_ws;     // NBLK floats of scratch

    hipLaunchKernelGGL(yolo_loss_kernel, dim3(NBLK), dim3(256), 0, stream,
                       pred, tgt, part);
    hipLaunchKernelGGL(reduce_kernel, dim3(1), dim3(256), 0, stream,
                       part, out);
}